// Round 5
// baseline (1340.187 us; speedup 1.0000x reference)
//
#include <hip/hip_runtime.h>
#include <hip/hip_bf16.h>
#include <cstdint>

#define N_NODES 20000
#define N_EDGES 100000
#define WALK 4
#define FDIM 256
#define HID 64
#define NHEAD 8
#define HR 512
#define OUTD 16

typedef __attribute__((ext_vector_type(8))) short bf16x8;
typedef __attribute__((ext_vector_type(8))) unsigned short u16x8;
typedef __attribute__((ext_vector_type(4))) float f32x4;

__device__ __forceinline__ float b2f(unsigned short u){
  union{float f; unsigned u;} x; x.u = ((unsigned)u)<<16; return x.f;
}
__device__ __forceinline__ unsigned short f2b(float f){
  union{float f; unsigned u;} x; x.f = f;
  unsigned r = x.u + 0x7FFFu + ((x.u>>16)&1u);
  return (unsigned short)(r>>16);
}
__device__ __forceinline__ float sigmoidf_(float v){ return 1.0f/(1.0f+__expf(-v)); }
__device__ __forceinline__ float tanh_c(float v){
  v = fminf(fmaxf(v, -15.f), 15.f);
  const float t2 = __expf(2.0f*v);
  return (t2 - 1.0f) / (t2 + 1.0f);
}

__device__ __forceinline__ void gload16(const void* g, void* l){
  __builtin_amdgcn_global_load_lds(
      (const __attribute__((address_space(1))) void*)(g),
      (__attribute__((address_space(3))) void*)(l),
      16, 0, 0);
}

__device__ __forceinline__ f32x4 mfma16(bf16x8 a, bf16x8 b, f32x4 c){
  return __builtin_amdgcn_mfma_f32_16x16x32_bf16(a, b, c, 0, 0, 0);
}

// ---------------- emb = bf16(x @ W_mlp.T + b_mlp)  (20000x64, linear) ----------------
__launch_bounds__(256)
__global__ void emb_kernel(const float* __restrict__ x,
                           const float* __restrict__ Wm,
                           const float* __restrict__ bm,
                           unsigned short* __restrict__ emb_bf)
{
  __shared__ float xs[4][FDIM];
  const int tid = threadIdx.x;
  const int node0 = blockIdx.x * 4;
  {
    const int row = tid >> 6;
    const int k4  = (tid & 63) * 4;
    *reinterpret_cast<float4*>(&xs[row][k4]) =
      *reinterpret_cast<const float4*>(&x[(size_t)(node0+row)*FDIM + k4]);
  }
  __syncthreads();
  const int nn = tid >> 6, c = tid & 63;
  float acc = bm[c];
  const float* wr = &Wm[c*FDIM];
  #pragma unroll 8
  for (int k=0;k<FDIM;k+=4){
    const float4 w = *reinterpret_cast<const float4*>(&wr[k]);
    acc += xs[nn][k]*w.x + xs[nn][k+1]*w.y + xs[nn][k+2]*w.z + xs[nn][k+3]*w.w;
  }
  emb_bf[(size_t)(node0+nn)*HID + c] = f2b(acc);
}

// ---------------- weight prep (bf16, gate-INTERLEAVED frag rows, chunk-swizzle) -------
__launch_bounds__(256)
__global__ void prep_kernel(const float* __restrict__ Whh,
                            const float* __restrict__ Wih,
                            const float* __restrict__ Wemb,
                            unsigned short* __restrict__ WhhP,
                            unsigned short* __restrict__ WihP,
                            unsigned short* __restrict__ WembP)
{
  const int t = blockIdx.x*256 + threadIdx.x;
  if (t < 8*192*512){
    const int k = t & 511;
    const int r = (t >> 9) % 192;
    const int db = t / 98304;
    const int f = r >> 4, fr = r & 15;
    const int g = f % 3, dgrp = f / 3;
    const int G = g*HR + db*64 + dgrp*16 + fr;
    const int kg = k >> 6, kw = k & 63;
    const int c = kw >> 3, o = kw & 7;
    const int ksrc = (kg<<6) + (((c ^ (r&7)) << 3) | o);
    WhhP[t] = f2b(Whh[(size_t)G*HR + ksrc]);
  }
  if (t < 8*192*64){
    const int k = t & 63;
    const int r = (t >> 6) % 192;
    const int db = t / 12288;
    const int f = r >> 4, fr = r & 15;
    const int g = f % 3, dgrp = f / 3;
    const int G = g*HR + db*64 + dgrp*16 + fr;
    const int c = k >> 3, o = k & 7;
    const int ksrc = (((c ^ (r&7)) << 3) | o);
    WihP[t] = f2b(Wih[(size_t)G*HID + ksrc]);
  }
  if (t < 64*512){
    const int k = t & 511;
    const int o = t >> 9;
    const int kg = k >> 6, kw = k & 63;
    const int c = kw >> 3, off = kw & 7;
    const int ksrc = (kg<<6) + (((c ^ (o&7)) << 3) | off);
    WembP[t] = f2b(Wemb[(size_t)o*HR + ksrc]);
  }
}

// ---------------- xg: per-node x-gates -> xnP (n-gate + b_ih_n) and h1n --------------
__launch_bounds__(512)
__global__ void xg_kernel(const unsigned short* __restrict__ emb_bf,
                          const unsigned short* __restrict__ WihP,
                          const float* __restrict__ b_ih,
                          const float* __restrict__ b_hh,
                          unsigned short* __restrict__ xnP,
                          unsigned short* __restrict__ h1n)
{
  __shared__ __align__(16) char smem[32768 + 24576];
  char* Ab = smem;
  char* Bb = smem + 32768;
  const int tid = threadIdx.x, lane = tid & 63, w = tid >> 6;
  const int wr = w >> 1, wn = w & 1;
  const int n0 = blockIdx.x * 256;
  const int db = blockIdx.y;

  #pragma unroll
  for (int j=0;j<4;++j){
    const int flat = j*512 + tid;
    const int row = flat >> 3, c = flat & 7;
    int n = n0 + row; if (n > N_NODES-1) n = N_NODES-1;
    gload16(emb_bf + ((size_t)n*HID + ((c ^ (row&7))<<3)), Ab + ((j*512 + w*64)<<4));
  }
  #pragma unroll
  for (int j=0;j<3;++j){
    const int flat = j*512 + tid;
    const int row = flat >> 3, c = flat & 7;
    gload16(WihP + ((size_t)(db*192 + row)*HID + c*8), Bb + ((j*512 + w*64)<<4));
  }
  asm volatile("s_waitcnt vmcnt(0)" ::: "memory");
  __builtin_amdgcn_s_barrier();

  f32x4 acc[4][6];
  #pragma unroll
  for (int m=0;m<4;++m)
    #pragma unroll
    for (int f=0;f<6;++f) acc[m][f] = (f32x4)(0.f);

  auto readFrag = [&](const char* base, int row, int kk)->bf16x8{
    const int chunk = (kk<<2) + (lane>>4);
    return *reinterpret_cast<const bf16x8*>(base + (row<<7) + ((chunk ^ (row&7))<<4));
  };
  #pragma unroll
  for (int kk=0; kk<2; ++kk){
    bf16x8 a_[4];
    #pragma unroll
    for (int mf=0; mf<4; ++mf) a_[mf] = readFrag(Ab, wr*64 + mf*16 + (lane&15), kk);
    #pragma unroll
    for (int nf=0; nf<6; ++nf){
      const bf16x8 b_ = readFrag(Bb, wn*96 + nf*16 + (lane&15), kk);
      #pragma unroll
      for (int mf=0; mf<4; ++mf) acc[mf][nf] = mfma16(a_[mf], b_, acc[mf][nf]);
    }
  }

  const int fr_ = lane & 15;
  #pragma unroll
  for (int mf=0; mf<4; ++mf){
    #pragma unroll
    for (int reg=0; reg<4; ++reg){
      const int row = wr*64 + mf*16 + ((lane>>4)<<2) + reg;
      const int n = n0 + row;
      if (n < N_NODES){
        #pragma unroll
        for (int t=0; t<2; ++t){
          const int d6 = (2*wn+t)*16 + fr_;
          const int dG = db*64 + d6;
          const float xr = acc[mf][t*3+0][reg] + b_ih[dG];
          const float xz = acc[mf][t*3+1][reg] + b_ih[HR+dG];
          const float xn = acc[mf][t*3+2][reg] + b_ih[2*HR+dG];
          xnP[((size_t)db*N_NODES + n)*64 + d6] = f2b(xn);
          const float r = sigmoidf_(xr + b_hh[dG]);
          const float z = sigmoidf_(xz + b_hh[HR+dG]);
          const float nn = tanh_c(xn + r*b_hh[2*HR+dG]);
          h1n[(size_t)n*HR + dG] = f2b((1.0f - z)*nn);
        }
      }
    }
  }
}

// ---------------- GRU step via MFMA: 128x192 tile, 2 blocks/CU, dbuf pipeline ---------
// 9 K-tiles: 0..7 = h (K=512), 8 = x (gathered emb; n-frags skipped).
// 8 waves: wr=w>>1 (32 rows each), wn=w&1 (96 cols each). acc[2][6] = 48 VGPR.
// LDS 80KB: A dbuf 2x16K @0, B dbuf 2x24K @32768 -> exactly 2 blocks/CU.
template<int STEP, bool SCORE>
__launch_bounds__(512, 4)
__global__ void gru_mfma(const unsigned short* __restrict__ emb_bf,
                         const int* __restrict__ idx,
                         const unsigned short* __restrict__ h_in,  // STEP==1: h1n per-node linear; else per-edge swizzled
                         unsigned short* __restrict__ h_out,
                         const unsigned short* __restrict__ WhhP,
                         const unsigned short* __restrict__ WihP,
                         const unsigned short* __restrict__ xnP,
                         const float* __restrict__ b_ih,
                         const float* __restrict__ b_hh,
                         const float* __restrict__ attn,
                         float* __restrict__ a_buf)
{
  constexpr bool GATHER = (STEP == 1);
  __shared__ __align__(16) char smem[81920];

  const int tid = threadIdx.x;
  const int lane = tid & 63;
  const int w = tid >> 6;
  const int wr = w >> 1, wn = w & 1;

  const int bid = blockIdx.x;
  const int sid = (bid & 7)*782 + (bid >> 3);   // bijective XCD swizzle (6256 = 8*782)
  const int et = sid >> 3;
  const int db = sid & 7;
  const int e0 = et * 128;

  // ---- preload idx-derived nodes for staging (no vmem inside the K-loop) ----
  int eS[2], nH[2], nX[2];
  #pragma unroll
  for (int j=0;j<2;++j){
    int e = e0 + ((j*512 + tid) >> 3);
    if (e > N_EDGES-1) e = N_EDGES-1;
    eS[j] = e;
    nX[j] = idx[e*WALK + STEP];
    nH[j] = GATHER ? idx[e*WALK] : 0;
  }

  f32x4 acc[2][6];
  #pragma unroll
  for (int m=0;m<2;++m)
    #pragma unroll
    for (int f=0;f<6;++f) acc[m][f] = (f32x4)(0.f);

  auto Abase = [&](int s)->char*{ return smem + s*16384; };
  auto Bbase = [&](int s)->char*{ return smem + 32768 + s*24576; };

  auto stage_A = [&](int slot, int kt){
    #pragma unroll
    for (int j=0;j<2;++j){
      const int flat = j*512 + tid;
      const int row = flat >> 3, c = flat & 7;
      const unsigned short* src;
      if (kt == 8){
        src = emb_bf + ((size_t)nX[j]*HID + ((c ^ (row&7)) << 3));
      } else if (GATHER){
        src = h_in + ((size_t)nH[j]*HR + kt*64 + ((c ^ (row&7)) << 3));
      } else {
        src = h_in + ((size_t)eS[j]*HR + kt*64 + c*8);
      }
      gload16(src, Abase(slot) + ((j*512 + w*64) << 4));
    }
  };
  auto stage_B = [&](int slot, int kt){
    #pragma unroll
    for (int j=0;j<3;++j){
      const int flat = j*512 + tid;
      const int row = flat >> 3, c = flat & 7;
      const unsigned short* src = (kt < 8)
        ? WhhP + ((size_t)(db*192 + row)*HR + kt*64 + c*8)
        : WihP + ((size_t)(db*192 + row)*HID + c*8);
      gload16(src, Bbase(slot) + ((j*512 + w*64) << 4));
    }
  };

  auto readFrag = [&](const char* base, int row, int kk)->bf16x8{
    const int chunk = (kk<<2) + (lane>>4);
    return *reinterpret_cast<const bf16x8*>(base + (row<<7) + ((chunk ^ (row&7))<<4));
  };

#define COMPUTE(ab, bb, kk, XS)                                               \
  {                                                                           \
    bf16x8 a_[2];                                                             \
    _Pragma("unroll")                                                         \
    for (int mf=0; mf<2; ++mf)                                                \
      a_[mf] = readFrag(ab, wr*32 + mf*16 + (lane&15), kk);                   \
    __builtin_amdgcn_s_setprio(1);                                            \
    _Pragma("unroll")                                                         \
    for (int nf=0; nf<6; ++nf){                                               \
      if (XS && (nf % 3) == 2) continue;                                      \
      const bf16x8 b_ = readFrag(bb, wn*96 + nf*16 + (lane&15), kk);          \
      _Pragma("unroll")                                                       \
      for (int mf=0; mf<2; ++mf)                                              \
        acc[mf][nf] = mfma16(a_[mf], b_, acc[mf][nf]);                        \
    }                                                                         \
    __builtin_amdgcn_s_setprio(0);                                            \
  }

  stage_A(0, 0); stage_B(0, 0);
  asm volatile("s_waitcnt vmcnt(0)" ::: "memory");
  __builtin_amdgcn_s_barrier();
  __builtin_amdgcn_sched_barrier(0);

  #pragma unroll
  for (int kt=0; kt<9; ++kt){
    const int buf = kt & 1;
    char* ab = Abase(buf);
    char* bb = Bbase(buf);
    if (kt < 8){ stage_A(buf^1, kt+1); stage_B(buf^1, kt+1); }
    if (kt==8){ COMPUTE(ab, bb, 0, true);  } else { COMPUTE(ab, bb, 0, false); }
    if (kt==8){ COMPUTE(ab, bb, 1, true);  } else { COMPUTE(ab, bb, 1, false); }
    if (kt < 8){
      asm volatile("s_waitcnt vmcnt(0)" ::: "memory");
      __builtin_amdgcn_s_barrier();
      __builtin_amdgcn_sched_barrier(0);
    }
  }
#undef COMPUTE

  // ---- epilogue: col-major f32 exchange in LDS (2 passes x 48KB), vectorized I/O ----
  // EX layout: [96 passcols][128 rows] f32; 16B row-chunks XOR-swizzled by (col&7).
  float* EX = (float*)smem;
  const int eL = tid & 127;            // edge-local
  const int c4 = tid >> 7;             // 0..3 : which 8-col chunk of the 32 pass-cols
  const int tt = c4 >> 1;              // dgroup within pass
  const int fr0 = (c4 & 1) * 8;
  const int eg = e0 + eL;
  const int ec = (eg > N_EDGES-1) ? (N_EDGES-1) : eg;
  float spart = 0.f;

  __syncthreads();

  #pragma unroll
  for (int p=0; p<2; ++p){
    if (p) __syncthreads();
    if (wn == p){
      #pragma unroll
      for (int mf=0; mf<2; ++mf){
        const int rc = wr*8 + mf*4 + (lane>>4);          // 16B row-chunk index
        #pragma unroll
        for (int nf=0; nf<6; ++nf){
          const int cl = nf*16 + (lane&15);
          *reinterpret_cast<f32x4*>((char*)EX + cl*512 + ((rc ^ (cl&7))<<4)) = acc[mf][nf];
        }
      }
    }
    __syncthreads();

    const int d60 = p*32 + c4*8;            // first of 8 output cols
    const int dG0 = db*64 + d60;

    // gates from LDS
    float gr[8], gz[8], gn[8];
    #pragma unroll
    for (int i=0;i<8;++i){
      const int clr = (tt*3+0)*16 + fr0 + i;
      const int clz = (tt*3+1)*16 + fr0 + i;
      const int cln = (tt*3+2)*16 + fr0 + i;
      const int psw = ((eL>>2) ^ i) << 4;
      const int wo  = (eL&3) * 4;
      gr[i] = *reinterpret_cast<const float*>((char*)EX + clr*512 + psw + wo);
      gz[i] = *reinterpret_cast<const float*>((char*)EX + clz*512 + psw + wo);
      gn[i] = *reinterpret_cast<const float*>((char*)EX + cln*512 + psw + wo);
    }

    // biases (L1-hot)
    float bir[8], biz[8], bhn[8];
    #pragma unroll
    for (int i=0;i<8;++i){
      bir[i] = b_ih[dG0+i]      + b_hh[dG0+i];
      biz[i] = b_ih[HR+dG0+i]   + b_hh[HR+dG0+i];
      bhn[i] = b_hh[2*HR+dG0+i];
    }

    // xn gather (per-node), hold
    const int nodeS = idx[ec*WALK + STEP];
    const u16x8 xnv = *reinterpret_cast<const u16x8*>(
        xnP + ((size_t)db*N_NODES + nodeS)*64 + d60);
    u16x8 hov;
    if (GATHER){
      const int nodeH = idx[ec*WALK];
      hov = *reinterpret_cast<const u16x8*>(h_in + (size_t)nodeH*HR + dG0);
    } else {
      const int cidx = d60 >> 3;
      hov = *reinterpret_cast<const u16x8*>(
          h_in + (size_t)ec*HR + db*64 + ((cidx ^ (ec&7))<<3));
    }

    union { u16x8 v; unsigned short s[8]; } outp;
    #pragma unroll
    for (int i=0;i<8;++i){
      const float r  = sigmoidf_(gr[i] + bir[i]);
      const float z  = sigmoidf_(gz[i] + biz[i]);
      const float hn = gn[i] + bhn[i];
      const float xn = b2f(xnv[i]);
      const float nn = tanh_c(xn + r*hn);
      const float hv = (1.0f - z)*nn + z*b2f(hov[i]);
      outp.s[i] = f2b(hv);
      if (SCORE) spart += hv * attn[dG0 + i];
    }
    if (eg < N_EDGES){
      const int cidx = d60 >> 3;
      *reinterpret_cast<u16x8*>(
          h_out + (size_t)eg*HR + db*64 + ((cidx ^ (eg&7))<<3)) = outp.v;
    }
  }

  if (SCORE && eg < N_EDGES){
    atomicAdd(&a_buf[eg*NHEAD + db], spart);
  }
}

// ---------------- score finalize: leaky-relu + segment max ----------------
__launch_bounds__(256)
__global__ void score2_kernel(const int* __restrict__ idx,
                              float* __restrict__ a_buf,
                              unsigned int* __restrict__ mmax)
{
  const int flat = blockIdx.x*256 + threadIdx.x;
  const int e = flat >> 3, h = flat & 7;
  const float s = a_buf[flat];
  const float a = s > 0.f ? s : 0.01f*s;
  a_buf[flat] = a;
  const int dst = idx[e*WALK + 3];
  union{float f; unsigned u;} x; x.f = a;
  const unsigned key = (x.u & 0x80000000u) ? ~x.u : (x.u | 0x80000000u);
  atomicMax(&mmax[dst*NHEAD + h], key);
}

// ---------------- exp(a-m) + segment sum ----------------
__launch_bounds__(256)
__global__ void ea_kernel(const int* __restrict__ idx,
                          float* __restrict__ a_buf,
                          const unsigned int* __restrict__ mmax,
                          float* __restrict__ ssum)
{
  const int flat = blockIdx.x*256 + threadIdx.x;
  const int e = flat >> 3, h = flat & 7;
  const int dst = idx[e*WALK + 3];
  const unsigned key = mmax[dst*NHEAD + h];
  union{float f; unsigned u;} x;
  x.u = (key & 0x80000000u) ? (key & 0x7FFFFFFFu) : ~key;
  const float ea = __expf(a_buf[flat] - x.f);
  a_buf[flat] = ea;
  atomicAdd(&ssum[dst*NHEAD + h], ea);
}

// ---------------- alpha = ea / ssum[dst]  (in place) ----------------
__launch_bounds__(256)
__global__ void alpha_kernel(const int* __restrict__ idx,
                             float* __restrict__ a_buf,
                             const float* __restrict__ ssum)
{
  const int flat = blockIdx.x*256 + threadIdx.x;
  const int e = flat >> 3, h = flat & 7;
  const int dst = idx[e*WALK + 3];
  a_buf[flat] = a_buf[flat] / ssum[dst*NHEAD + h];
}

// ---------------- z[e] = (hT[e]*alpha) @ Wemb.T ; zacc[dst] += z[e] ----------------
__launch_bounds__(256)
__global__ void z_kernel(const unsigned short* __restrict__ hT,
                         const int* __restrict__ idx,
                         const float* __restrict__ alpha,
                         const unsigned short* __restrict__ WembP,
                         float* __restrict__ zacc)
{
  __shared__ __align__(16) char zs[40960];  // Az 32768 + Bz 8192
  char* Az = zs;
  char* Bz = zs + 32768;
  const int tid = threadIdx.x;
  const int lane = tid & 63;
  const int w = tid >> 6;
  const int e0 = blockIdx.x * 256;

  f32x4 acc[4][4];
  #pragma unroll
  for (int m=0;m<4;++m)
    #pragma unroll
    for (int f=0;f<4;++f) acc[m][f] = (f32x4)(0.f);

  auto readFrag = [&](const char* base, int row, int kk)->bf16x8{
    const int chunk = (kk<<2) + (lane>>4);
    return *reinterpret_cast<const bf16x8*>(base + (row<<7) + ((chunk ^ (row&7))<<4));
  };

  #pragma unroll 1
  for (int kt=0; kt<8; ++kt){
    __syncthreads();
    #pragma unroll
    for (int j=0;j<8;++j){
      const int flat = j*256 + tid;
      const int row = flat >> 3, c = flat & 7;
      int e = e0 + row; if (e > N_EDGES-1) e = N_EDGES-1;
      const u16x8 hv = *reinterpret_cast<const u16x8*>(hT + (size_t)e*HR + kt*64 + c*8);
      const float al = alpha[e*NHEAD + kt];
      union { bf16x8 v; unsigned short s[8]; } o;
      #pragma unroll
      for (int i=0;i<8;++i) o.s[i] = f2b(b2f(hv[i]) * al);
      *reinterpret_cast<bf16x8*>(Az + flat*16) = o.v;
    }
    #pragma unroll
    for (int j=0;j<2;++j){
      const int flat = j*256 + tid;
      const int row = flat >> 3, c = flat & 7;
      gload16(WembP + ((size_t)row*HR + kt*64 + c*8), Bz + ((j*256 + w*64)<<4));
    }
    __syncthreads();
    #pragma unroll
    for (int kk=0; kk<2; ++kk){
      bf16x8 a_[4];
      #pragma unroll
      for (int mf=0; mf<4; ++mf)
        a_[mf] = readFrag(Az, w*64 + mf*16 + (lane&15), kk);
      #pragma unroll
      for (int nf=0; nf<4; ++nf){
        const bf16x8 b_ = readFrag(Bz, nf*16 + (lane&15), kk);
        #pragma unroll
        for (int mf=0; mf<4; ++mf)
          acc[mf][nf] = mfma16(a_[mf], b_, acc[mf][nf]);
      }
    }
  }

  #pragma unroll
  for (int mf=0; mf<4; ++mf){
    #pragma unroll
    for (int reg=0; reg<4; ++reg){
      const int row = w*64 + mf*16 + ((lane>>4)<<2) + reg;
      const int e = e0 + row;
      if (e < N_EDGES){
        const int dst = idx[e*WALK + 3];
        #pragma unroll
        for (int nf=0; nf<4; ++nf){
          const int o = nf*16 + (lane&15);
          atomicAdd(&zacc[(size_t)dst*64 + o], acc[mf][nf][reg]);
        }
      }
    }
  }
}

// ---------------- out = (zacc + b_emb) @ W_last.T + b_last ----------------
__launch_bounds__(256)
__global__ void out2_kernel(const float* __restrict__ zacc,
                            const float* __restrict__ b_emb,
                            const float* __restrict__ W_last,
                            const float* __restrict__ b_last,
                            float* __restrict__ out)
{
  const int flat = blockIdx.x*256 + threadIdx.x;
  if (flat >= N_NODES*OUTD) return;
  const int n = flat >> 4, o = flat & 15;
  float s = b_last[o];
  const float* zr = &zacc[(size_t)n*64];
  const float* wl = &W_last[o*64];
  #pragma unroll
  for (int k=0;k<64;++k) s += (zr[k] + b_emb[k]) * wl[k];
  out[(size_t)n*OUTD + o] = s;
}

// ---------------- launch ----------------
extern "C" void kernel_launch(void* const* d_in, const int* in_sizes, int n_in,
                              void* d_out, int out_size, void* d_ws, size_t ws_size,
                              hipStream_t stream)
{
  (void)in_sizes; (void)n_in; (void)out_size; (void)ws_size;
  const float* x      = (const float*)d_in[0];
  const float* W_mlp  = (const float*)d_in[1];
  const float* b_mlp  = (const float*)d_in[2];
  const float* W_ih   = (const float*)d_in[3];
  const float* W_hh   = (const float*)d_in[4];
  const float* b_ih   = (const float*)d_in[5];
  const float* b_hh   = (const float*)d_in[6];
  const float* attn   = (const float*)d_in[7];
  const float* W_emb  = (const float*)d_in[8];
  const float* b_emb  = (const float*)d_in[9];
  const float* W_last = (const float*)d_in[10];
  const float* b_last = (const float*)d_in[11];
  const int*   idx    = (const int*)d_in[12];
  float* out = (float*)d_out;

  char* ws = (char*)d_ws;
  unsigned short* WhhP   = (unsigned short*)(ws + 0);            //   1,572,864
  unsigned short* WihP   = (unsigned short*)(ws + 1572864);      //     196,608
  unsigned short* WembP  = (unsigned short*)(ws + 1769472);      //      65,536
  unsigned short* emb_bf = (unsigned short*)(ws + 1835008);      //   2,560,000
  unsigned short* xnP    = (unsigned short*)(ws + 4395008);      //  20,480,000
  float*          a_buf  = (float*)(ws + 24875008);              //   3,200,000
  unsigned int*   mmax   = (unsigned int*)(ws + 28075008);       //     640,000
  float*          ssum   = (float*)(ws + 28715008);              //     640,000
  float*          zacc   = (float*)(ws + 29355008);              //   5,120,000
  unsigned short* h_a    = (unsigned short*)(ws + 34475008);     // 102,400,000
  unsigned short* h_b    = (unsigned short*)(ws + 136875008);    // 102,400,000
  unsigned short* h1n    = h_b;  // alias: h1n dead before gru step 2 writes h_b
  // total = 239,275,008 B

  // zero a_buf + mmax + ssum + zacc (contiguous 9.6 MB)
  hipMemsetAsync(a_buf, 0, 9600000, stream);

  prep_kernel<<<3072, 256, 0, stream>>>(W_hh, W_ih, W_emb, WhhP, WihP, WembP);
  emb_kernel<<<N_NODES/4, 256, 0, stream>>>(x, W_mlp, b_mlp, emb_bf);

  dim3 xgrid(79, 8);
  xg_kernel<<<xgrid, 512, 0, stream>>>(emb_bf, WihP, b_ih, b_hh, xnP, h1n);

  const int NWG = 782*8;  // 6256 blocks: 782 edge-tiles x 8 d-blocks
  gru_mfma<1,false><<<NWG, 512, 0, stream>>>(emb_bf, idx, h1n, h_a, WhhP, WihP, xnP, b_ih, b_hh, attn, a_buf);
  gru_mfma<2,false><<<NWG, 512, 0, stream>>>(emb_bf, idx, h_a, h_b, WhhP, WihP, xnP, b_ih, b_hh, attn, a_buf);
  gru_mfma<3,true ><<<NWG, 512, 0, stream>>>(emb_bf, idx, h_b, h_a, WhhP, WihP, xnP, b_ih, b_hh, attn, a_buf);
  // hT (swizzled) in h_a; raw scores summed in a_buf

  score2_kernel<<<N_EDGES*NHEAD/256, 256, 0, stream>>>(idx, a_buf, mmax);
  ea_kernel<<<N_EDGES*NHEAD/256, 256, 0, stream>>>(idx, a_buf, mmax, ssum);
  alpha_kernel<<<N_EDGES*NHEAD/256, 256, 0, stream>>>(idx, a_buf, ssum);
  z_kernel<<<391, 256, 0, stream>>>(h_a, idx, a_buf, WembP, zacc);
  out2_kernel<<<(N_NODES*OUTD+255)/256, 256, 0, stream>>>(zacc, b_emb, W_last, b_last, out);
}

// Round 6
// 1221.726 us; speedup vs baseline: 1.0970x; 1.0970x over previous
//
#include <hip/hip_runtime.h>
#include <hip/hip_bf16.h>
#include <cstdint>

#define N_NODES 20000
#define N_EDGES 100000
#define WALK 4
#define FDIM 256
#define HID 64
#define NHEAD 8
#define HR 512
#define OUTD 16

typedef __attribute__((ext_vector_type(8))) short bf16x8;
typedef __attribute__((ext_vector_type(8))) unsigned short u16x8;
typedef __attribute__((ext_vector_type(4))) float f32x4;

__device__ __forceinline__ float b2f(unsigned short u){
  union{float f; unsigned u;} x; x.u = ((unsigned)u)<<16; return x.f;
}
__device__ __forceinline__ unsigned short f2b(float f){
  union{float f; unsigned u;} x; x.f = f;
  unsigned r = x.u + 0x7FFFu + ((x.u>>16)&1u);
  return (unsigned short)(r>>16);
}
__device__ __forceinline__ float sigmoidf_(float v){ return 1.0f/(1.0f+__expf(-v)); }
__device__ __forceinline__ float tanh_c(float v){
  v = fminf(fmaxf(v, -15.f), 15.f);
  const float t2 = __expf(2.0f*v);
  return (t2 - 1.0f) / (t2 + 1.0f);
}

__device__ __forceinline__ void gload16(const void* g, void* l){
  __builtin_amdgcn_global_load_lds(
      (const __attribute__((address_space(1))) void*)(g),
      (__attribute__((address_space(3))) void*)(l),
      16, 0, 0);
}

__device__ __forceinline__ f32x4 mfma16(bf16x8 a, bf16x8 b, f32x4 c){
  return __builtin_amdgcn_mfma_f32_16x16x32_bf16(a, b, c, 0, 0, 0);
}

// ---------------- emb = bf16(x @ W_mlp.T + b_mlp)  (20000x64, linear) ----------------
__launch_bounds__(256)
__global__ void emb_kernel(const float* __restrict__ x,
                           const float* __restrict__ Wm,
                           const float* __restrict__ bm,
                           unsigned short* __restrict__ emb_bf)
{
  __shared__ float xs[4][FDIM];
  const int tid = threadIdx.x;
  const int node0 = blockIdx.x * 4;
  {
    const int row = tid >> 6;
    const int k4  = (tid & 63) * 4;
    *reinterpret_cast<float4*>(&xs[row][k4]) =
      *reinterpret_cast<const float4*>(&x[(size_t)(node0+row)*FDIM + k4]);
  }
  __syncthreads();
  const int nn = tid >> 6, c = tid & 63;
  float acc = bm[c];
  const float* wr = &Wm[c*FDIM];
  #pragma unroll 8
  for (int k=0;k<FDIM;k+=4){
    const float4 w = *reinterpret_cast<const float4*>(&wr[k]);
    acc += xs[nn][k]*w.x + xs[nn][k+1]*w.y + xs[nn][k+2]*w.z + xs[nn][k+3]*w.w;
  }
  emb_bf[(size_t)(node0+nn)*HID + c] = f2b(acc);
}

// ---------------- weight prep (bf16, gate-INTERLEAVED frag rows, chunk-swizzle) -------
__launch_bounds__(256)
__global__ void prep_kernel(const float* __restrict__ Whh,
                            const float* __restrict__ Wih,
                            const float* __restrict__ Wemb,
                            unsigned short* __restrict__ WhhP,
                            unsigned short* __restrict__ WihP,
                            unsigned short* __restrict__ WembP)
{
  const int t = blockIdx.x*256 + threadIdx.x;
  if (t < 8*192*512){
    const int k = t & 511;
    const int r = (t >> 9) % 192;
    const int db = t / 98304;
    const int f = r >> 4, fr = r & 15;
    const int g = f % 3, dgrp = f / 3;
    const int G = g*HR + db*64 + dgrp*16 + fr;
    const int kg = k >> 6, kw = k & 63;
    const int c = kw >> 3, o = kw & 7;
    const int ksrc = (kg<<6) + (((c ^ (r&7)) << 3) | o);
    WhhP[t] = f2b(Whh[(size_t)G*HR + ksrc]);
  }
  if (t < 8*192*64){
    const int k = t & 63;
    const int r = (t >> 6) % 192;
    const int db = t / 12288;
    const int f = r >> 4, fr = r & 15;
    const int g = f % 3, dgrp = f / 3;
    const int G = g*HR + db*64 + dgrp*16 + fr;
    const int c = k >> 3, o = k & 7;
    const int ksrc = (((c ^ (r&7)) << 3) | o);
    WihP[t] = f2b(Wih[(size_t)G*HID + ksrc]);
  }
  if (t < 64*512){
    const int k = t & 511;
    const int o = t >> 9;
    const int kg = k >> 6, kw = k & 63;
    const int c = kw >> 3, off = kw & 7;
    const int ksrc = (kg<<6) + (((c ^ (o&7)) << 3) | off);
    WembP[t] = f2b(Wemb[(size_t)o*HR + ksrc]);
  }
}

// ---------------- xg: per-node x-gates -> xnP (n-gate + b_ih_n) and h1n --------------
__launch_bounds__(512)
__global__ void xg_kernel(const unsigned short* __restrict__ emb_bf,
                          const unsigned short* __restrict__ WihP,
                          const float* __restrict__ b_ih,
                          const float* __restrict__ b_hh,
                          unsigned short* __restrict__ xnP,
                          unsigned short* __restrict__ h1n)
{
  __shared__ __align__(16) char smem[32768 + 24576];
  char* Ab = smem;
  char* Bb = smem + 32768;
  const int tid = threadIdx.x, lane = tid & 63, w = tid >> 6;
  const int wr = w >> 1, wn = w & 1;
  const int n0 = blockIdx.x * 256;
  const int db = blockIdx.y;

  #pragma unroll
  for (int j=0;j<4;++j){
    const int flat = j*512 + tid;
    const int row = flat >> 3, c = flat & 7;
    int n = n0 + row; if (n > N_NODES-1) n = N_NODES-1;
    gload16(emb_bf + ((size_t)n*HID + ((c ^ (row&7))<<3)), Ab + ((j*512 + w*64)<<4));
  }
  #pragma unroll
  for (int j=0;j<3;++j){
    const int flat = j*512 + tid;
    const int row = flat >> 3, c = flat & 7;
    gload16(WihP + ((size_t)(db*192 + row)*HID + c*8), Bb + ((j*512 + w*64)<<4));
  }
  asm volatile("s_waitcnt vmcnt(0)" ::: "memory");
  __builtin_amdgcn_s_barrier();

  f32x4 acc[4][6];
  #pragma unroll
  for (int m=0;m<4;++m)
    #pragma unroll
    for (int f=0;f<6;++f) acc[m][f] = (f32x4)(0.f);

  auto readFrag = [&](const char* base, int row, int kk)->bf16x8{
    const int chunk = (kk<<2) + (lane>>4);
    return *reinterpret_cast<const bf16x8*>(base + (row<<7) + ((chunk ^ (row&7))<<4));
  };
  #pragma unroll
  for (int kk=0; kk<2; ++kk){
    bf16x8 a_[4];
    #pragma unroll
    for (int mf=0; mf<4; ++mf) a_[mf] = readFrag(Ab, wr*64 + mf*16 + (lane&15), kk);
    #pragma unroll
    for (int nf=0; nf<6; ++nf){
      const bf16x8 b_ = readFrag(Bb, wn*96 + nf*16 + (lane&15), kk);
      #pragma unroll
      for (int mf=0; mf<4; ++mf) acc[mf][nf] = mfma16(a_[mf], b_, acc[mf][nf]);
    }
  }

  const int fr_ = lane & 15;
  #pragma unroll
  for (int mf=0; mf<4; ++mf){
    #pragma unroll
    for (int reg=0; reg<4; ++reg){
      const int row = wr*64 + mf*16 + ((lane>>4)<<2) + reg;
      const int n = n0 + row;
      if (n < N_NODES){
        #pragma unroll
        for (int t=0; t<2; ++t){
          const int d6 = (2*wn+t)*16 + fr_;
          const int dG = db*64 + d6;
          const float xr = acc[mf][t*3+0][reg] + b_ih[dG];
          const float xz = acc[mf][t*3+1][reg] + b_ih[HR+dG];
          const float xn = acc[mf][t*3+2][reg] + b_ih[2*HR+dG];
          xnP[((size_t)db*N_NODES + n)*64 + d6] = f2b(xn);
          const float r = sigmoidf_(xr + b_hh[dG]);
          const float z = sigmoidf_(xz + b_hh[HR+dG]);
          const float nn = tanh_c(xn + r*b_hh[2*HR+dG]);
          h1n[(size_t)n*HR + dG] = f2b((1.0f - z)*nn);
        }
      }
    }
  }
}

// ---------------- GRU step via MFMA: 128x192 tile, 2 blocks/CU, dbuf pipeline ---------
// 9 K-tiles: 0..7 = h (K=512), 8 = x (gathered emb; n-frags skipped).
// 8 waves: wr=w>>1 (32 rows each), wn=w&1 (96 cols each). acc[2][6] = 48 VGPR.
// LDS 80KB: A dbuf 2x16K @0, B dbuf 2x24K @32768 -> 2 blocks/CU (LDS-bound).
// NOTE: __launch_bounds__ 2nd arg: (512,4) empirically capped VGPR at 64 -> spill
// (R5: 770MB FETCH / 833MB WRITE scratch). (512,2) -> 128 cap, ~108 used, no spill.
template<int STEP, bool SCORE>
__launch_bounds__(512, 2)
__global__ void gru_mfma(const unsigned short* __restrict__ emb_bf,
                         const int* __restrict__ idx,
                         const unsigned short* __restrict__ h_in,  // STEP==1: h1n per-node linear; else per-edge swizzled
                         unsigned short* __restrict__ h_out,
                         const unsigned short* __restrict__ WhhP,
                         const unsigned short* __restrict__ WihP,
                         const unsigned short* __restrict__ xnP,
                         const float* __restrict__ b_ih,
                         const float* __restrict__ b_hh,
                         const float* __restrict__ attn,
                         float* __restrict__ a_buf)
{
  constexpr bool GATHER = (STEP == 1);
  __shared__ __align__(16) char smem[81920];

  const int tid = threadIdx.x;
  const int lane = tid & 63;
  const int w = tid >> 6;
  const int wr = w >> 1, wn = w & 1;

  const int bid = blockIdx.x;
  const int sid = (bid & 7)*782 + (bid >> 3);   // bijective XCD swizzle (6256 = 8*782)
  const int et = sid >> 3;
  const int db = sid & 7;
  const int e0 = et * 128;

  // ---- preload idx-derived nodes for staging (no vmem inside the K-loop) ----
  int eS[2], nH[2], nX[2];
  #pragma unroll
  for (int j=0;j<2;++j){
    int e = e0 + ((j*512 + tid) >> 3);
    if (e > N_EDGES-1) e = N_EDGES-1;
    eS[j] = e;
    nX[j] = idx[e*WALK + STEP];
    nH[j] = GATHER ? idx[e*WALK] : 0;
  }

  f32x4 acc[2][6];
  #pragma unroll
  for (int m=0;m<2;++m)
    #pragma unroll
    for (int f=0;f<6;++f) acc[m][f] = (f32x4)(0.f);

  auto Abase = [&](int s)->char*{ return smem + s*16384; };
  auto Bbase = [&](int s)->char*{ return smem + 32768 + s*24576; };

  auto stage_A = [&](int slot, int kt){
    #pragma unroll
    for (int j=0;j<2;++j){
      const int flat = j*512 + tid;
      const int row = flat >> 3, c = flat & 7;
      const unsigned short* src;
      if (kt == 8){
        src = emb_bf + ((size_t)nX[j]*HID + ((c ^ (row&7)) << 3));
      } else if (GATHER){
        src = h_in + ((size_t)nH[j]*HR + kt*64 + ((c ^ (row&7)) << 3));
      } else {
        src = h_in + ((size_t)eS[j]*HR + kt*64 + c*8);
      }
      gload16(src, Abase(slot) + ((j*512 + w*64) << 4));
    }
  };
  auto stage_B = [&](int slot, int kt){
    #pragma unroll
    for (int j=0;j<3;++j){
      const int flat = j*512 + tid;
      const int row = flat >> 3, c = flat & 7;
      const unsigned short* src = (kt < 8)
        ? WhhP + ((size_t)(db*192 + row)*HR + kt*64 + c*8)
        : WihP + ((size_t)(db*192 + row)*HID + c*8);
      gload16(src, Bbase(slot) + ((j*512 + w*64) << 4));
    }
  };

  auto readFrag = [&](const char* base, int row, int kk)->bf16x8{
    const int chunk = (kk<<2) + (lane>>4);
    return *reinterpret_cast<const bf16x8*>(base + (row<<7) + ((chunk ^ (row&7))<<4));
  };

#define COMPUTE(ab, bb, kk, XS)                                               \
  {                                                                           \
    bf16x8 a_[2];                                                             \
    _Pragma("unroll")                                                         \
    for (int mf=0; mf<2; ++mf)                                                \
      a_[mf] = readFrag(ab, wr*32 + mf*16 + (lane&15), kk);                   \
    __builtin_amdgcn_s_setprio(1);                                            \
    _Pragma("unroll")                                                         \
    for (int nf=0; nf<6; ++nf){                                               \
      if (XS && (nf % 3) == 2) continue;                                      \
      const bf16x8 b_ = readFrag(bb, wn*96 + nf*16 + (lane&15), kk);          \
      _Pragma("unroll")                                                       \
      for (int mf=0; mf<2; ++mf)                                              \
        acc[mf][nf] = mfma16(a_[mf], b_, acc[mf][nf]);                        \
    }                                                                         \
    __builtin_amdgcn_s_setprio(0);                                            \
  }

  stage_A(0, 0); stage_B(0, 0);
  asm volatile("s_waitcnt vmcnt(0)" ::: "memory");
  __builtin_amdgcn_s_barrier();
  __builtin_amdgcn_sched_barrier(0);

  #pragma unroll
  for (int kt=0; kt<9; ++kt){
    const int buf = kt & 1;
    char* ab = Abase(buf);
    char* bb = Bbase(buf);
    if (kt < 8){ stage_A(buf^1, kt+1); stage_B(buf^1, kt+1); }
    if (kt==8){ COMPUTE(ab, bb, 0, true);  } else { COMPUTE(ab, bb, 0, false); }
    if (kt==8){ COMPUTE(ab, bb, 1, true);  } else { COMPUTE(ab, bb, 1, false); }
    if (kt < 8){
      asm volatile("s_waitcnt vmcnt(0)" ::: "memory");
      __builtin_amdgcn_s_barrier();
      __builtin_amdgcn_sched_barrier(0);
    }
  }
#undef COMPUTE

  // ---- epilogue: col-major f32 exchange in LDS (2 passes x 48KB), vectorized I/O ----
  // EX layout: [96 passcols][128 rows] f32; 16B row-chunks XOR-swizzled by (col&7).
  float* EX = (float*)smem;
  const int eL = tid & 127;            // edge-local
  const int c4 = tid >> 7;             // 0..3 : which 8-col chunk of the 32 pass-cols
  const int tt = c4 >> 1;              // dgroup within pass
  const int fr0 = (c4 & 1) * 8;
  const int eg = e0 + eL;
  const int ec = (eg > N_EDGES-1) ? (N_EDGES-1) : eg;
  float spart = 0.f;

  __syncthreads();

  #pragma unroll
  for (int p=0; p<2; ++p){
    if (p) __syncthreads();
    if (wn == p){
      #pragma unroll
      for (int mf=0; mf<2; ++mf){
        const int rc = wr*8 + mf*4 + (lane>>4);          // 16B row-chunk index
        #pragma unroll
        for (int nf=0; nf<6; ++nf){
          const int cl = nf*16 + (lane&15);
          *reinterpret_cast<f32x4*>((char*)EX + cl*512 + ((rc ^ (cl&7))<<4)) = acc[mf][nf];
        }
      }
    }
    __syncthreads();

    const int d60 = p*32 + c4*8;            // first of 8 output cols
    const int dG0 = db*64 + d60;

    // gates from LDS
    float gr[8], gz[8], gn[8];
    #pragma unroll
    for (int i=0;i<8;++i){
      const int clr = (tt*3+0)*16 + fr0 + i;
      const int clz = (tt*3+1)*16 + fr0 + i;
      const int cln = (tt*3+2)*16 + fr0 + i;
      const int psw = ((eL>>2) ^ i) << 4;
      const int wo  = (eL&3) * 4;
      gr[i] = *reinterpret_cast<const float*>((char*)EX + clr*512 + psw + wo);
      gz[i] = *reinterpret_cast<const float*>((char*)EX + clz*512 + psw + wo);
      gn[i] = *reinterpret_cast<const float*>((char*)EX + cln*512 + psw + wo);
    }

    // biases (L1-hot)
    float bir[8], biz[8], bhn[8];
    #pragma unroll
    for (int i=0;i<8;++i){
      bir[i] = b_ih[dG0+i]      + b_hh[dG0+i];
      biz[i] = b_ih[HR+dG0+i]   + b_hh[HR+dG0+i];
      bhn[i] = b_hh[2*HR+dG0+i];
    }

    // xn gather (per-node), hold
    const int nodeS = idx[ec*WALK + STEP];
    const u16x8 xnv = *reinterpret_cast<const u16x8*>(
        xnP + ((size_t)db*N_NODES + nodeS)*64 + d60);
    u16x8 hov;
    if (GATHER){
      const int nodeH = idx[ec*WALK];
      hov = *reinterpret_cast<const u16x8*>(h_in + (size_t)nodeH*HR + dG0);
    } else {
      const int cidx = d60 >> 3;
      hov = *reinterpret_cast<const u16x8*>(
          h_in + (size_t)ec*HR + db*64 + ((cidx ^ (ec&7))<<3));
    }

    union { u16x8 v; unsigned short s[8]; } outp;
    #pragma unroll
    for (int i=0;i<8;++i){
      const float r  = sigmoidf_(gr[i] + bir[i]);
      const float z  = sigmoidf_(gz[i] + biz[i]);
      const float hn = gn[i] + bhn[i];
      const float xn = b2f(xnv[i]);
      const float nn = tanh_c(xn + r*hn);
      const float hv = (1.0f - z)*nn + z*b2f(hov[i]);
      outp.s[i] = f2b(hv);
      if (SCORE) spart += hv * attn[dG0 + i];
    }
    if (eg < N_EDGES){
      const int cidx = d60 >> 3;
      *reinterpret_cast<u16x8*>(
          h_out + (size_t)eg*HR + db*64 + ((cidx ^ (eg&7))<<3)) = outp.v;
    }
  }

  if (SCORE && eg < N_EDGES){
    atomicAdd(&a_buf[eg*NHEAD + db], spart);
  }
}

// ---------------- score finalize: leaky-relu + segment max ----------------
__launch_bounds__(256)
__global__ void score2_kernel(const int* __restrict__ idx,
                              float* __restrict__ a_buf,
                              unsigned int* __restrict__ mmax)
{
  const int flat = blockIdx.x*256 + threadIdx.x;
  const int e = flat >> 3, h = flat & 7;
  const float s = a_buf[flat];
  const float a = s > 0.f ? s : 0.01f*s;
  a_buf[flat] = a;
  const int dst = idx[e*WALK + 3];
  union{float f; unsigned u;} x; x.f = a;
  const unsigned key = (x.u & 0x80000000u) ? ~x.u : (x.u | 0x80000000u);
  atomicMax(&mmax[dst*NHEAD + h], key);
}

// ---------------- exp(a-m) + segment sum ----------------
__launch_bounds__(256)
__global__ void ea_kernel(const int* __restrict__ idx,
                          float* __restrict__ a_buf,
                          const unsigned int* __restrict__ mmax,
                          float* __restrict__ ssum)
{
  const int flat = blockIdx.x*256 + threadIdx.x;
  const int e = flat >> 3, h = flat & 7;
  const int dst = idx[e*WALK + 3];
  const unsigned key = mmax[dst*NHEAD + h];
  union{float f; unsigned u;} x;
  x.u = (key & 0x80000000u) ? (key & 0x7FFFFFFFu) : ~key;
  const float ea = __expf(a_buf[flat] - x.f);
  a_buf[flat] = ea;
  atomicAdd(&ssum[dst*NHEAD + h], ea);
}

// ---------------- alpha = ea / ssum[dst]  (in place) ----------------
__launch_bounds__(256)
__global__ void alpha_kernel(const int* __restrict__ idx,
                             float* __restrict__ a_buf,
                             const float* __restrict__ ssum)
{
  const int flat = blockIdx.x*256 + threadIdx.x;
  const int e = flat >> 3, h = flat & 7;
  const int dst = idx[e*WALK + 3];
  a_buf[flat] = a_buf[flat] / ssum[dst*NHEAD + h];
}

// ---------------- z[e] = (hT[e]*alpha) @ Wemb.T ; zacc[dst] += z[e] ----------------
__launch_bounds__(256)
__global__ void z_kernel(const unsigned short* __restrict__ hT,
                         const int* __restrict__ idx,
                         const float* __restrict__ alpha,
                         const unsigned short* __restrict__ WembP,
                         float* __restrict__ zacc)
{
  __shared__ __align__(16) char zs[40960];  // Az 32768 + Bz 8192
  char* Az = zs;
  char* Bz = zs + 32768;
  const int tid = threadIdx.x;
  const int lane = tid & 63;
  const int w = tid >> 6;
  const int e0 = blockIdx.x * 256;

  f32x4 acc[4][4];
  #pragma unroll
  for (int m=0;m<4;++m)
    #pragma unroll
    for (int f=0;f<4;++f) acc[m][f] = (f32x4)(0.f);

  auto readFrag = [&](const char* base, int row, int kk)->bf16x8{
    const int chunk = (kk<<2) + (lane>>4);
    return *reinterpret_cast<const bf16x8*>(base + (row<<7) + ((chunk ^ (row&7))<<4));
  };

  #pragma unroll 1
  for (int kt=0; kt<8; ++kt){
    __syncthreads();
    #pragma unroll
    for (int j=0;j<8;++j){
      const int flat = j*256 + tid;
      const int row = flat >> 3, c = flat & 7;
      int e = e0 + row; if (e > N_EDGES-1) e = N_EDGES-1;
      const u16x8 hv = *reinterpret_cast<const u16x8*>(hT + (size_t)e*HR + kt*64 + c*8);
      const float al = alpha[e*NHEAD + kt];
      union { bf16x8 v; unsigned short s[8]; } o;
      #pragma unroll
      for (int i=0;i<8;++i) o.s[i] = f2b(b2f(hv[i]) * al);
      *reinterpret_cast<bf16x8*>(Az + flat*16) = o.v;
    }
    #pragma unroll
    for (int j=0;j<2;++j){
      const int flat = j*256 + tid;
      const int row = flat >> 3, c = flat & 7;
      gload16(WembP + ((size_t)row*HR + kt*64 + c*8), Bz + ((j*256 + w*64)<<4));
    }
    __syncthreads();
    #pragma unroll
    for (int kk=0; kk<2; ++kk){
      bf16x8 a_[4];
      #pragma unroll
      for (int mf=0; mf<4; ++mf)
        a_[mf] = readFrag(Az, w*64 + mf*16 + (lane&15), kk);
      #pragma unroll
      for (int nf=0; nf<4; ++nf){
        const bf16x8 b_ = readFrag(Bz, nf*16 + (lane&15), kk);
        #pragma unroll
        for (int mf=0; mf<4; ++mf)
          acc[mf][nf] = mfma16(a_[mf], b_, acc[mf][nf]);
      }
    }
  }

  #pragma unroll
  for (int mf=0; mf<4; ++mf){
    #pragma unroll
    for (int reg=0; reg<4; ++reg){
      const int row = w*64 + mf*16 + ((lane>>4)<<2) + reg;
      const int e = e0 + row;
      if (e < N_EDGES){
        const int dst = idx[e*WALK + 3];
        #pragma unroll
        for (int nf=0; nf<4; ++nf){
          const int o = nf*16 + (lane&15);
          atomicAdd(&zacc[(size_t)dst*64 + o], acc[mf][nf][reg]);
        }
      }
    }
  }
}

// ---------------- out = (zacc + b_emb) @ W_last.T + b_last ----------------
__launch_bounds__(256)
__global__ void out2_kernel(const float* __restrict__ zacc,
                            const float* __restrict__ b_emb,
                            const float* __restrict__ W_last,
                            const float* __restrict__ b_last,
                            float* __restrict__ out)
{
  const int flat = blockIdx.x*256 + threadIdx.x;
  if (flat >= N_NODES*OUTD) return;
  const int n = flat >> 4, o = flat & 15;
  float s = b_last[o];
  const float* zr = &zacc[(size_t)n*64];
  const float* wl = &W_last[o*64];
  #pragma unroll
  for (int k=0;k<64;++k) s += (zr[k] + b_emb[k]) * wl[k];
  out[(size_t)n*OUTD + o] = s;
}

// ---------------- launch ----------------
extern "C" void kernel_launch(void* const* d_in, const int* in_sizes, int n_in,
                              void* d_out, int out_size, void* d_ws, size_t ws_size,
                              hipStream_t stream)
{
  (void)in_sizes; (void)n_in; (void)out_size; (void)ws_size;
  const float* x      = (const float*)d_in[0];
  const float* W_mlp  = (const float*)d_in[1];
  const float* b_mlp  = (const float*)d_in[2];
  const float* W_ih   = (const float*)d_in[3];
  const float* W_hh   = (const float*)d_in[4];
  const float* b_ih   = (const float*)d_in[5];
  const float* b_hh   = (const float*)d_in[6];
  const float* attn   = (const float*)d_in[7];
  const float* W_emb  = (const float*)d_in[8];
  const float* b_emb  = (const float*)d_in[9];
  const float* W_last = (const float*)d_in[10];
  const float* b_last = (const float*)d_in[11];
  const int*   idx    = (const int*)d_in[12];
  float* out = (float*)d_out;

  char* ws = (char*)d_ws;
  unsigned short* WhhP   = (unsigned short*)(ws + 0);            //   1,572,864
  unsigned short* WihP   = (unsigned short*)(ws + 1572864);      //     196,608
  unsigned short* WembP  = (unsigned short*)(ws + 1769472);      //      65,536
  unsigned short* emb_bf = (unsigned short*)(ws + 1835008);      //   2,560,000
  unsigned short* xnP    = (unsigned short*)(ws + 4395008);      //  20,480,000
  float*          a_buf  = (float*)(ws + 24875008);              //   3,200,000
  unsigned int*   mmax   = (unsigned int*)(ws + 28075008);       //     640,000
  float*          ssum   = (float*)(ws + 28715008);              //     640,000
  float*          zacc   = (float*)(ws + 29355008);              //   5,120,000
  unsigned short* h_a    = (unsigned short*)(ws + 34475008);     // 102,400,000
  unsigned short* h_b    = (unsigned short*)(ws + 136875008);    // 102,400,000
  unsigned short* h1n    = h_b;  // alias: h1n dead before gru step 2 writes h_b
  // total = 239,275,008 B

  // zero a_buf + mmax + ssum + zacc (contiguous 9.6 MB)
  hipMemsetAsync(a_buf, 0, 9600000, stream);

  prep_kernel<<<3072, 256, 0, stream>>>(W_hh, W_ih, W_emb, WhhP, WihP, WembP);
  emb_kernel<<<N_NODES/4, 256, 0, stream>>>(x, W_mlp, b_mlp, emb_bf);

  dim3 xgrid(79, 8);
  xg_kernel<<<xgrid, 512, 0, stream>>>(emb_bf, WihP, b_ih, b_hh, xnP, h1n);

  const int NWG = 782*8;  // 6256 blocks: 782 edge-tiles x 8 d-blocks
  gru_mfma<1,false><<<NWG, 512, 0, stream>>>(emb_bf, idx, h1n, h_a, WhhP, WihP, xnP, b_ih, b_hh, attn, a_buf);
  gru_mfma<2,false><<<NWG, 512, 0, stream>>>(emb_bf, idx, h_a, h_b, WhhP, WihP, xnP, b_ih, b_hh, attn, a_buf);
  gru_mfma<3,true ><<<NWG, 512, 0, stream>>>(emb_bf, idx, h_b, h_a, WhhP, WihP, xnP, b_ih, b_hh, attn, a_buf);
  // hT (swizzled) in h_a; raw scores summed in a_buf

  score2_kernel<<<N_EDGES*NHEAD/256, 256, 0, stream>>>(idx, a_buf, mmax);
  ea_kernel<<<N_EDGES*NHEAD/256, 256, 0, stream>>>(idx, a_buf, mmax, ssum);
  alpha_kernel<<<N_EDGES*NHEAD/256, 256, 0, stream>>>(idx, a_buf, ssum);
  z_kernel<<<391, 256, 0, stream>>>(h_a, idx, a_buf, WembP, zacc);
  out2_kernel<<<(N_NODES*OUTD+255)/256, 256, 0, stream>>>(zacc, b_emb, W_last, b_last, out);
}